// Round 1
// baseline (22.399 us; speedup 1.0000x reference)
//
#include <hip/hip_runtime.h>

// Problem constants (from reference): B=8, N=256, MO=64, D=128
#define PB 8
#define PN 256
#define PMO 64
#define PD 128
#define PV (PD / 4)          // 32 float4 per (b,n,pos) row
// total float4 elements in new_buffer
#define TOTAL_V4 ((long)PB * PN * PMO * PV)   // 4,194,304

__global__ void combinator_buf_kernel(const float* __restrict__ left_buf,
                                      const float* __restrict__ left_count,
                                      const float* __restrict__ right_buf,
                                      const float* __restrict__ right_count,
                                      const int* __restrict__ subs,
                                      float* __restrict__ out_buf) {
    long g = (long)blockIdx.x * blockDim.x + threadIdx.x;
    if (g >= TOTAL_V4) return;

    int v   = (int)(g & (PV - 1));        // float4 lane within row
    long row = g >> 5;                    // / PV
    int pos = (int)(row & (PMO - 1));     // position within MO
    int bn  = (int)(row >> 6);            // / PMO  -> flat (b,n)

    int s = subs[bn];
    float lc = left_count[bn];
    float rc = right_count[bn];
    float fcf = (s == 1) ? rc : lc;
    float scf = (s == 1) ? lc : rc;
    int fc = max((int)rintf(fcf), 0);     // round-half-even, matches jnp.round
    int sc = max((int)rintf(scf), 0);

    const float4* first  = (const float4*)((s == 1) ? right_buf : left_buf);
    const float4* second = (const float4*)((s == 1) ? left_buf  : right_buf);

    float4 out = make_float4(0.f, 0.f, 0.f, 0.f);
    if (pos < fc) {
        // identity gather == first_buf[pos]
        out = first[((long)bn * PMO + pos) * PV + v];
    } else if (pos < fc + sc) {
        int idx = pos - fc;               // in [0, MO-1] here; clip is a no-op
        out = second[((long)bn * PMO + idx) * PV + v];
    }
    ((float4*)out_buf)[g] = out;
}

__global__ void combinator_count_kernel(const float* __restrict__ left_count,
                                        const float* __restrict__ right_count,
                                        const int* __restrict__ subs,
                                        float* __restrict__ out_count) {
    int i = blockIdx.x * blockDim.x + threadIdx.x;
    if (i >= PB * PN) return;
    int s = subs[i];
    float lc = left_count[i];
    float rc = right_count[i];
    float fcf = (s == 1) ? rc : lc;
    float scf = (s == 1) ? lc : rc;
    out_count[i] = fminf(fcf + scf, (float)PMO);
}

extern "C" void kernel_launch(void* const* d_in, const int* in_sizes, int n_in,
                              void* d_out, int out_size, void* d_ws, size_t ws_size,
                              hipStream_t stream) {
    const float* left_buf    = (const float*)d_in[0];
    const float* left_count  = (const float*)d_in[1];
    const float* right_buf   = (const float*)d_in[2];
    const float* right_count = (const float*)d_in[3];
    const int*   subs        = (const int*)d_in[4];

    float* out_buf   = (float*)d_out;
    float* out_count = out_buf + (long)PB * PN * PMO * PD;

    const int block = 256;
    long grid = (TOTAL_V4 + block - 1) / block;   // 16384 blocks
    combinator_buf_kernel<<<(int)grid, block, 0, stream>>>(
        left_buf, left_count, right_buf, right_count, subs, out_buf);

    int cgrid = (PB * PN + block - 1) / block;    // 8 blocks
    combinator_count_kernel<<<cgrid, block, 0, stream>>>(
        left_count, right_count, subs, out_count);
}

// Round 2
// 20.162 us; speedup vs baseline: 1.1110x; 1.1110x over previous
//
#include <hip/hip_runtime.h>

// Problem constants (from reference): B=8, N=256, MO=64, D=128
#define PB 8
#define PN 256
#define PMO 64
#define PD 128
#define PV (PD / 4)            // 32 float4 per (b,n,pos) row
#define ROW_V4 (PMO * PV)      // 2048 float4 per (b,n)
#define BLOCK 256
#define ITERS (ROW_V4 / BLOCK) // 8

__global__ __launch_bounds__(BLOCK)
void combinator_fused_kernel(const float* __restrict__ left_buf,
                             const float* __restrict__ left_count,
                             const float* __restrict__ right_buf,
                             const float* __restrict__ right_count,
                             const int* __restrict__ subs,
                             float* __restrict__ out_buf,
                             float* __restrict__ out_count) {
    int bn = blockIdx.x;                  // flat (b,n), 0..2047 — block-uniform
    int s  = subs[bn];                    // uniform -> scalar load
    float lc = left_count[bn];
    float rc = right_count[bn];
    float fcf = (s == 1) ? rc : lc;
    float scf = (s == 1) ? lc : rc;
    int fc = max((int)rintf(fcf), 0);     // round-half-even == jnp.round
    int sc = max((int)rintf(scf), 0);
    int lim = fc + sc;                    // <= 64 given fc,sc <= 32

    if (threadIdx.x == 0)
        out_count[bn] = fminf(fcf + scf, (float)PMO);

    long base = (long)bn * ROW_V4;
    const float4* first  = (const float4*)((s == 1) ? right_buf : left_buf) + base;
    const float4* second = (const float4*)((s == 1) ? left_buf  : right_buf) + base;
    float4* out = (float4*)out_buf + base;

    int fshift = fc << 5;                 // fc * PV

    #pragma unroll
    for (int i = 0; i < ITERS; ++i) {
        int idx = threadIdx.x + i * BLOCK;   // 0..2047
        int pos = idx >> 5;                  // row within MO
        float4 o = make_float4(0.f, 0.f, 0.f, 0.f);
        if (pos < fc) {
            o = first[idx];                  // identity gather
        } else if (pos < lim) {
            o = second[idx - fshift];        // shifted row, still coalesced
        }
        out[idx] = o;
    }
}

extern "C" void kernel_launch(void* const* d_in, const int* in_sizes, int n_in,
                              void* d_out, int out_size, void* d_ws, size_t ws_size,
                              hipStream_t stream) {
    const float* left_buf    = (const float*)d_in[0];
    const float* left_count  = (const float*)d_in[1];
    const float* right_buf   = (const float*)d_in[2];
    const float* right_count = (const float*)d_in[3];
    const int*   subs        = (const int*)d_in[4];

    float* out_buf   = (float*)d_out;
    float* out_count = out_buf + (long)PB * PN * PMO * PD;

    combinator_fused_kernel<<<PB * PN, BLOCK, 0, stream>>>(
        left_buf, left_count, right_buf, right_count, subs, out_buf, out_count);
}

// Round 3
// 20.068 us; speedup vs baseline: 1.1162x; 1.0046x over previous
//
#include <hip/hip_runtime.h>

// Problem constants (from reference): B=8, N=256, MO=64, D=128
#define PB 8
#define PN 256
#define PMO 64
#define PD 128
#define PV (PD / 4)            // 32 float4 per (b,n,pos) row
#define ROW_V4 (PMO * PV)      // 2048 float4 per (b,n)
#define BLOCK 256
#define ITERS (ROW_V4 / BLOCK) // 8

typedef float f4 __attribute__((ext_vector_type(4)));

__global__ __launch_bounds__(BLOCK)
void combinator_fused_kernel(const float* __restrict__ left_buf,
                             const float* __restrict__ left_count,
                             const float* __restrict__ right_buf,
                             const float* __restrict__ right_count,
                             const int* __restrict__ subs,
                             float* __restrict__ out_buf,
                             float* __restrict__ out_count) {
    int bn = blockIdx.x;                  // flat (b,n), 0..2047 — block-uniform
    int s  = subs[bn];                    // uniform -> scalar load
    float lc = left_count[bn];
    float rc = right_count[bn];
    float fcf = (s == 1) ? rc : lc;
    float scf = (s == 1) ? lc : rc;
    int fc = max((int)rintf(fcf), 0);     // round-half-even == jnp.round
    int sc = max((int)rintf(scf), 0);
    int lim = fc + sc;                    // <= 64 since fc,sc <= 32

    if (threadIdx.x == 0)
        out_count[bn] = fminf(fcf + scf, (float)PMO);

    int base = bn << 11;                  // * ROW_V4 (fits in int: max 4.19M)
    const f4* first  = (const f4*)((s == 1) ? right_buf : left_buf) + base;
    const f4* second = (const f4*)((s == 1) ? left_buf  : right_buf) + base;
    f4* out = (f4*)out_buf + base;

    int end1 = fc  << 5;                  // v4-units end of first region
    int end2 = lim << 5;                  // v4-units end of second region

    #pragma unroll
    for (int i = 0; i < ITERS; ++i) {
        int idx = (int)threadIdx.x + (i << 8);   // 0..2047
        f4 o = (f4)(0.0f);
        if (idx < end1) {
            o = first[idx];                      // identity gather, in-bounds
        } else if (idx < end2) {
            o = second[idx - end1];              // shifted row, coalesced
        }
        __builtin_nontemporal_store(o, out + idx);  // streaming store, skip L2 pollution
    }
}

extern "C" void kernel_launch(void* const* d_in, const int* in_sizes, int n_in,
                              void* d_out, int out_size, void* d_ws, size_t ws_size,
                              hipStream_t stream) {
    const float* left_buf    = (const float*)d_in[0];
    const float* left_count  = (const float*)d_in[1];
    const float* right_buf   = (const float*)d_in[2];
    const float* right_count = (const float*)d_in[3];
    const int*   subs        = (const int*)d_in[4];

    float* out_buf   = (float*)d_out;
    float* out_count = out_buf + (long)PB * PN * PMO * PD;

    combinator_fused_kernel<<<PB * PN, BLOCK, 0, stream>>>(
        left_buf, left_count, right_buf, right_count, subs, out_buf, out_count);
}

// Round 4
// 18.481 us; speedup vs baseline: 1.2120x; 1.0859x over previous
//
#include <hip/hip_runtime.h>

// Problem constants (from reference): B=8, N=256, MO=64, D=128
#define PB 8
#define PN 256
#define PMO 64
#define PD 128
#define PV (PD / 4)            // 32 float4 per (b,n,pos) row
#define ROW_V4 (PMO * PV)      // 2048 float4 per (b,n)
#define BLOCK 256
#define ITERS (ROW_V4 / BLOCK) // 8

typedef float f4 __attribute__((ext_vector_type(4)));

__global__ __launch_bounds__(BLOCK)
void combinator_fused_kernel(const float* __restrict__ left_buf,
                             const float* __restrict__ left_count,
                             const float* __restrict__ right_buf,
                             const float* __restrict__ right_count,
                             const int* __restrict__ subs,
                             float* __restrict__ out_buf,
                             float* __restrict__ out_count) {
    int bn = blockIdx.x;                  // flat (b,n), 0..2047 — block-uniform
    int s  = subs[bn];                    // uniform -> scalar load
    float lc = left_count[bn];
    float rc = right_count[bn];
    float fcf = (s == 1) ? rc : lc;
    float scf = (s == 1) ? lc : rc;
    int fc = max((int)rintf(fcf), 0);     // round-half-even == jnp.round
    int sc = max((int)rintf(scf), 0);
    int lim = fc + sc;                    // <= 64 since fc,sc <= 32

    if (threadIdx.x == 0)
        out_count[bn] = fminf(fcf + scf, (float)PMO);

    int base = bn << 11;                  // * ROW_V4
    const f4* first  = (const f4*)((s == 1) ? right_buf : left_buf) + base;
    const f4* second = (const f4*)((s == 1) ? left_buf  : right_buf) + base;
    f4* out = (f4*)out_buf + base;

    int end1 = fc  << 5;                  // v4-units end of first region
    int end2 = lim << 5;                  // v4-units end of second region
    int sc32m1 = max((sc << 5) - 1, 0);   // clamp bound for second-region index

    int tid = (int)threadIdx.x;
    #pragma unroll
    for (int i = 0; i < ITERS; ++i) {
        int idx = tid + (i << 8);                      // 0..2047
        // Branchless: one always-in-bounds load + select.
        int j2 = idx - end1;
        int j2c = max(0, min(j2, sc32m1));             // in [0, sc*32) or 0
        const f4* p = (idx < end1) ? (first + idx) : (second + j2c);
        f4 o = *p;
        o = (idx < end2) ? o : (f4)(0.0f);             // zero tail via cndmask
        __builtin_nontemporal_store(o, out + idx);
    }
}

extern "C" void kernel_launch(void* const* d_in, const int* in_sizes, int n_in,
                              void* d_out, int out_size, void* d_ws, size_t ws_size,
                              hipStream_t stream) {
    const float* left_buf    = (const float*)d_in[0];
    const float* left_count  = (const float*)d_in[1];
    const float* right_buf   = (const float*)d_in[2];
    const float* right_count = (const float*)d_in[3];
    const int*   subs        = (const int*)d_in[4];

    float* out_buf   = (float*)d_out;
    float* out_count = out_buf + (long)PB * PN * PMO * PD;

    combinator_fused_kernel<<<PB * PN, BLOCK, 0, stream>>>(
        left_buf, left_count, right_buf, right_count, subs, out_buf, out_count);
}